// Round 1
// 698.784 us; speedup vs baseline: 1.1490x; 1.1490x over previous
//
#include <hip/hip_runtime.h>
#include <stdint.h>

#define M_DIM 4096
#define K_DIM 4096
#define N_DIM 12288
#define BM 128
#define BN 128
#define BK 64

typedef __attribute__((ext_vector_type(8))) _Float16 half8;
typedef __attribute__((ext_vector_type(2))) __fp16 fp16x2;
typedef __attribute__((ext_vector_type(4))) float f32x4;

#define GLOAD_LDS16(gp, lp)                                                   \
  __builtin_amdgcn_global_load_lds(                                           \
      (const __attribute__((address_space(1))) void*)(gp),                    \
      (__attribute__((address_space(3))) void*)(lp), 16, 0, 0)

// 8 nibbles (high-first) -> 8 f16 weights, single-rounded:
// h = 1024 + n exactly (0x6400|n); (h - 1024) is exact; one mul rounds.
static __device__ __forceinline__ half8 dequant8(uint32_t q, _Float16 sh) {
  union { uint32_t u[4]; half8 h; } w;
  w.u[0] = 0x64006400u | ((q >> 28) & 0xFu) | ((q >> 8)  & 0xF0000u);
  w.u[1] = 0x64006400u | ((q >> 20) & 0xFu) | ( q         & 0xF0000u);
  w.u[2] = 0x64006400u | ((q >> 12) & 0xFu) | ((q << 8)  & 0xF0000u);
  w.u[3] = 0x64006400u | ((q >> 4)  & 0xFu) | ((q << 16) & 0xF0000u);
  half8 hv = w.h;
  half8 mm, ss;
  #pragma unroll
  for (int i = 0; i < 8; ++i) { mm[i] = (_Float16)(-1024.0f); ss[i] = sh; }
  return (hv + mm) * ss;   // pk_add_f16 + pk_mul_f16, vectorized
}

__global__ __launch_bounds__(256) void cvt_f32_f16(const float* __restrict__ X,
                                                   _Float16* __restrict__ XH) {
  const size_t i = ((size_t)blockIdx.x * 256 + threadIdx.x) * 8;
  f32x4 v0 = *(const f32x4*)(X + i);
  f32x4 v1 = *(const f32x4*)(X + i + 4);
  union { fp16x2 h2[4]; half8 h8; } u;
  u.h2[0] = __builtin_amdgcn_cvt_pkrtz(v0.x, v0.y);
  u.h2[1] = __builtin_amdgcn_cvt_pkrtz(v0.z, v0.w);
  u.h2[2] = __builtin_amdgcn_cvt_pkrtz(v1.x, v1.y);
  u.h2[3] = __builtin_amdgcn_cvt_pkrtz(v1.z, v1.w);
  *(half8*)(XH + i) = u.h8;
}

// One-shot weight dequant: one thread per packed int32 -> 8 f16 (16 B store).
// Coalesced Q dword loads, coalesced half8 stores, S broadcast per 16 lanes.
__global__ __launch_bounds__(256) void dequant_w(const int* __restrict__ Q,
                                                 const float* __restrict__ S,
                                                 _Float16* __restrict__ WH) {
  const int idx = blockIdx.x * 256 + threadIdx.x;  // [0, 12288*512)
  const int o = idx >> 9;    // output row (O)
  const int c = idx & 511;   // chunk within row (I/8)
  const uint32_t q = (uint32_t)Q[idx];
  const float s = S[o * (K_DIM / 128) + (c >> 4)];  // group = c*8/128 = c>>4
  *(half8*)(WH + (size_t)o * K_DIM + c * 8) = dequant8(q, (_Float16)s);
}

// Pure f16 GEMM: both operands pre-converted, both staged via
// global_load_lds (16 B) with the inverse-swizzled SOURCE address so the
// fragment ds_read_b128 is 2-way max (free). Same 2-barrier structure as
// before, minus all dequant / ds_write VALU work.
__global__ __launch_bounds__(256) void gemm_f16(
    const _Float16* __restrict__ XH, const _Float16* __restrict__ WH,
    const float* __restrict__ Bias, float* __restrict__ C) {
  __shared__ half8 As[BM * 8];
  __shared__ half8 Bs[BN * 8];

  const int tid  = threadIdx.x;
  const int lane = tid & 63;
  const int wave = tid >> 6;
  const int wm   = (wave >> 1) * 64;
  const int wn   = (wave & 1) * 64;
  const int m0   = blockIdx.y * BM;
  const int n0   = blockIdx.x * BN;
  const int rrow = lane & 15;
  const int quad = lane >> 4;

  // Per-lane source pointers: lane l of wave w, call r stages LDS slot
  // s=(w*4+r)*64+l; that slot's (row, chunk) gives the global chunk via the
  // inverse swizzle c = (s&7) ^ (row&7).
  const _Float16* a_gp[4];
  const _Float16* b_gp[4];
  #pragma unroll
  for (int r = 0; r < 4; ++r) {
    const int slot = (wave * 4 + r) * 64 + lane;
    const int row  = slot >> 3;
    const int c    = (slot & 7) ^ (row & 7);
    a_gp[r] = XH + (size_t)(m0 + row) * K_DIM + c * 8;
    b_gp[r] = WH + (size_t)(n0 + row) * K_DIM + c * 8;
  }

  f32x4 acc[4][4];
  #pragma unroll
  for (int i = 0; i < 4; ++i)
    #pragma unroll
    for (int j = 0; j < 4; ++j)
      acc[i][j] = (f32x4){0.f, 0.f, 0.f, 0.f};

  for (int k0 = 0; k0 < K_DIM; k0 += BK) {
    #pragma unroll
    for (int r = 0; r < 4; ++r)
      GLOAD_LDS16(a_gp[r] + k0, &As[(wave * 4 + r) * 64]);
    #pragma unroll
    for (int r = 0; r < 4; ++r)
      GLOAD_LDS16(b_gp[r] + k0, &Bs[(wave * 4 + r) * 64]);
    __syncthreads();

    #pragma unroll
    for (int kk = 0; kk < 2; ++kk) {
      const int kch = kk * 4 + quad;
      half8 a[4], b[4];
      #pragma unroll
      for (int mi = 0; mi < 4; ++mi) {
        const int row = wm + mi * 16 + rrow;
        a[mi] = As[row * 8 + (kch ^ (row & 7))];
      }
      #pragma unroll
      for (int ni = 0; ni < 4; ++ni) {
        const int row = wn + ni * 16 + rrow;
        b[ni] = Bs[row * 8 + (kch ^ (row & 7))];
      }
      #pragma unroll
      for (int mi = 0; mi < 4; ++mi)
        #pragma unroll
        for (int ni = 0; ni < 4; ++ni)
          acc[mi][ni] = __builtin_amdgcn_mfma_f32_16x16x32_f16(
              a[mi], b[ni], acc[mi][ni], 0, 0, 0);
    }
    __syncthreads();
  }

  // ---- epilogue: C/D layout col(n)=lane&15, row(m)=quad*4+reg [m89] ----
  #pragma unroll
  for (int ni = 0; ni < 4; ++ni) {
    const int n = n0 + wn + ni * 16 + rrow;
    const float bv = Bias[n];
    #pragma unroll
    for (int mi = 0; mi < 4; ++mi) {
      const int mbase = m0 + wm + mi * 16 + quad * 4;
      #pragma unroll
      for (int rr = 0; rr < 4; ++rr) {
        C[(size_t)(mbase + rr) * N_DIM + n] = acc[mi][ni][rr] + bv;
      }
    }
  }
}

// ---------------- fallback (previous verified kernel) ----------------
template <bool PRE>
__global__ __launch_bounds__(256) void awq_gemm(
    const float* __restrict__ X, const _Float16* __restrict__ XH,
    const int* __restrict__ Q, const float* __restrict__ S,
    const float* __restrict__ Bias, float* __restrict__ C) {
  __shared__ half8 As[BM * 8];
  __shared__ half8 Bs[BN * 8];

  const int tid  = threadIdx.x;
  const int lane = tid & 63;
  const int wave = tid >> 6;
  const int wm   = (wave >> 1) * 64;
  const int wn   = (wave & 1) * 64;
  const int m0   = blockIdx.y * BM;
  const int n0   = blockIdx.x * BN;
  const int rrow = lane & 15;
  const int quad = lane >> 4;

  const _Float16* a_gp[4];
  if (PRE) {
    #pragma unroll
    for (int r = 0; r < 4; ++r) {
      const int slot = (wave * 4 + r) * 64 + lane;
      const int row  = slot >> 3;
      const int c    = (slot & 7) ^ (row & 7);
      a_gp[r] = XH + (size_t)(m0 + row) * K_DIM + c * 8;
    }
  }

  int brow[4], bcol[4];
  #pragma unroll
  for (int r = 0; r < 4; ++r) {
    const int idx = tid + 256 * r;
    brow[r] = idx >> 3;
    bcol[r] = idx & 7;
  }

  f32x4 acc[4][4];
  #pragma unroll
  for (int i = 0; i < 4; ++i)
    #pragma unroll
    for (int j = 0; j < 4; ++j)
      acc[i][j] = (f32x4){0.f, 0.f, 0.f, 0.f};

  for (int k0 = 0; k0 < K_DIM; k0 += BK) {
    if (PRE) {
      #pragma unroll
      for (int r = 0; r < 4; ++r)
        GLOAD_LDS16(a_gp[r] + k0, &As[(wave * 4 + r) * 64]);
    } else {
      #pragma unroll
      for (int r = 0; r < 4; ++r) {
        const int ch  = tid + 256 * r;
        const int row = ch >> 3;
        const int c   = ch & 7;
        const float* p = X + (size_t)(m0 + row) * K_DIM + k0 + c * 8;
        f32x4 v0 = *(const f32x4*)p;
        f32x4 v1 = *(const f32x4*)(p + 4);
        union { fp16x2 h2[4]; half8 h8; } u;
        u.h2[0] = __builtin_amdgcn_cvt_pkrtz(v0.x, v0.y);
        u.h2[1] = __builtin_amdgcn_cvt_pkrtz(v0.z, v0.w);
        u.h2[2] = __builtin_amdgcn_cvt_pkrtz(v1.x, v1.y);
        u.h2[3] = __builtin_amdgcn_cvt_pkrtz(v1.z, v1.w);
        As[row * 8 + (c ^ (row & 7))] = u.h8;
      }
    }
    #pragma unroll
    for (int r = 0; r < 4; ++r) {
      const int row = brow[r];
      const int c   = bcol[r];
      const uint32_t q =
          (uint32_t)Q[(size_t)(n0 + row) * (K_DIM / 8) + (k0 >> 3) + c];
      const float s = S[(size_t)(n0 + row) * (K_DIM / 128) + (k0 >> 7)];
      Bs[row * 8 + (c ^ (row & 7))] = dequant8(q, (_Float16)s);
    }
    __syncthreads();

    #pragma unroll
    for (int kk = 0; kk < 2; ++kk) {
      const int kch = kk * 4 + quad;
      half8 a[4], b[4];
      #pragma unroll
      for (int mi = 0; mi < 4; ++mi) {
        const int row = wm + mi * 16 + rrow;
        a[mi] = As[row * 8 + (kch ^ (row & 7))];
      }
      #pragma unroll
      for (int ni = 0; ni < 4; ++ni) {
        const int row = wn + ni * 16 + rrow;
        b[ni] = Bs[row * 8 + (kch ^ (row & 7))];
      }
      #pragma unroll
      for (int mi = 0; mi < 4; ++mi)
        #pragma unroll
        for (int ni = 0; ni < 4; ++ni)
          acc[mi][ni] = __builtin_amdgcn_mfma_f32_16x16x32_f16(
              a[mi], b[ni], acc[mi][ni], 0, 0, 0);
    }
    __syncthreads();
  }

  #pragma unroll
  for (int ni = 0; ni < 4; ++ni) {
    const int n = n0 + wn + ni * 16 + rrow;
    const float bv = Bias[n];
    #pragma unroll
    for (int mi = 0; mi < 4; ++mi) {
      const int mbase = m0 + wm + mi * 16 + quad * 4;
      #pragma unroll
      for (int rr = 0; rr < 4; ++rr) {
        C[(size_t)(mbase + rr) * N_DIM + n] = acc[mi][ni][rr] + bv;
      }
    }
  }
}

extern "C" void kernel_launch(void* const* d_in, const int* in_sizes, int n_in,
                              void* d_out, int out_size, void* d_ws, size_t ws_size,
                              hipStream_t stream) {
  const float* X    = (const float*)d_in[0];
  const int*   Q    = (const int*)d_in[1];
  const float* S    = (const float*)d_in[2];
  const float* Bias = (const float*)d_in[3];
  float* C = (float*)d_out;
  dim3 grid(N_DIM / BN, M_DIM / BM);  // (96, 32)

  const size_t needXH  = (size_t)M_DIM * K_DIM * sizeof(_Float16);  // 32 MiB
  const size_t needWH  = (size_t)N_DIM * K_DIM * sizeof(_Float16);  // 96 MiB
  if (ws_size >= needXH + needWH) {
    _Float16* XH = (_Float16*)d_ws;
    _Float16* WH = (_Float16*)((char*)d_ws + needXH);
    cvt_f32_f16<<<(M_DIM * (size_t)K_DIM) / 8 / 256, 256, 0, stream>>>(X, XH);
    dequant_w<<<(N_DIM * (size_t)(K_DIM / 8)) / 256, 256, 0, stream>>>(Q, S, WH);
    gemm_f16<<<grid, dim3(256), 0, stream>>>(XH, WH, Bias, C);
  } else if (ws_size >= needXH) {
    _Float16* XH = (_Float16*)d_ws;
    cvt_f32_f16<<<(M_DIM * (size_t)K_DIM) / 8 / 256, 256, 0, stream>>>(X, XH);
    awq_gemm<true><<<grid, dim3(256), 0, stream>>>(X, XH, Q, S, Bias, C);
  } else {
    awq_gemm<false><<<grid, dim3(256), 0, stream>>>(X, nullptr, Q, S, Bias, C);
  }
}

// Round 3
// 622.955 us; speedup vs baseline: 1.2889x; 1.1217x over previous
//
#include <hip/hip_runtime.h>
#include <stdint.h>

#define M_DIM 4096
#define K_DIM 4096
#define N_DIM 12288

// fallback tile (old verified 128^2 kernel)
#define BM 128
#define BN 128
#define BK 64

typedef __attribute__((ext_vector_type(8))) _Float16 half8;
typedef __attribute__((ext_vector_type(2))) __fp16 fp16x2;
typedef __attribute__((ext_vector_type(4))) float f32x4;

#define GLOAD_LDS16(gp, lp)                                                   \
  __builtin_amdgcn_global_load_lds(                                           \
      (const __attribute__((address_space(1))) void*)(gp),                    \
      (__attribute__((address_space(3))) void*)(lp), 16, 0, 0)

// 8 nibbles (high-first) -> 8 f16 weights, single-rounded:
// h = 1024 + n exactly (0x6400|n); (h - 1024) is exact; one mul rounds.
static __device__ __forceinline__ half8 dequant8(uint32_t q, _Float16 sh) {
  union { uint32_t u[4]; half8 h; } w;
  w.u[0] = 0x64006400u | ((q >> 28) & 0xFu) | ((q >> 8)  & 0xF0000u);
  w.u[1] = 0x64006400u | ((q >> 20) & 0xFu) | ( q         & 0xF0000u);
  w.u[2] = 0x64006400u | ((q >> 12) & 0xFu) | ((q << 8)  & 0xF0000u);
  w.u[3] = 0x64006400u | ((q >> 4)  & 0xFu) | ((q << 16) & 0xF0000u);
  half8 hv = w.h;
  half8 mm, ss;
  #pragma unroll
  for (int i = 0; i < 8; ++i) { mm[i] = (_Float16)(-1024.0f); ss[i] = sh; }
  return (hv + mm) * ss;   // pk_add_f16 + pk_mul_f16, vectorized
}

// Merged prep: blocks [0,8192) convert X f32->f16; blocks [8192,32768)
// dequantize W (one thread per packed int32 -> 16 B f16 store).
__global__ __launch_bounds__(256) void prep(const float* __restrict__ X,
                                            _Float16* __restrict__ XH,
                                            const int* __restrict__ Q,
                                            const float* __restrict__ S,
                                            _Float16* __restrict__ WH) {
  const int bid = blockIdx.x;
  if (bid < 8192) {
    const size_t i = ((size_t)bid * 256 + threadIdx.x) * 8;
    f32x4 v0 = *(const f32x4*)(X + i);
    f32x4 v1 = *(const f32x4*)(X + i + 4);
    union { fp16x2 h2[4]; half8 h8; } u;
    u.h2[0] = __builtin_amdgcn_cvt_pkrtz(v0.x, v0.y);
    u.h2[1] = __builtin_amdgcn_cvt_pkrtz(v0.z, v0.w);
    u.h2[2] = __builtin_amdgcn_cvt_pkrtz(v1.x, v1.y);
    u.h2[3] = __builtin_amdgcn_cvt_pkrtz(v1.z, v1.w);
    *(half8*)(XH + i) = u.h8;
  } else {
    const int idx = (bid - 8192) * 256 + threadIdx.x;  // [0, 12288*512)
    const int o = idx >> 9;    // output row (O)
    const int c = idx & 511;   // chunk within row (I/8)
    const uint32_t q = (uint32_t)Q[idx];
    const float s = S[o * (K_DIM / 128) + (c >> 4)];
    *(half8*)(WH + (size_t)o * K_DIM + c * 8) = dequant8(q, (_Float16)s);
  }
}

// f32->f16 only (fallback path)
__global__ __launch_bounds__(256) void cvt_f32_f16(const float* __restrict__ X,
                                                   _Float16* __restrict__ XH) {
  const size_t i = ((size_t)blockIdx.x * 256 + threadIdx.x) * 8;
  f32x4 v0 = *(const f32x4*)(X + i);
  f32x4 v1 = *(const f32x4*)(X + i + 4);
  union { fp16x2 h2[4]; half8 h8; } u;
  u.h2[0] = __builtin_amdgcn_cvt_pkrtz(v0.x, v0.y);
  u.h2[1] = __builtin_amdgcn_cvt_pkrtz(v0.z, v0.w);
  u.h2[2] = __builtin_amdgcn_cvt_pkrtz(v1.x, v1.y);
  u.h2[3] = __builtin_amdgcn_cvt_pkrtz(v1.z, v1.w);
  *(half8*)(XH + i) = u.h8;
}

// ===================== 256x256 8-phase GEMM (T2+T3+T4+T5) =====================
// 512 threads = 8 waves (2M x 4N), per-wave output 128x64.
// LDS: double-buffered A/B K-tiles (BK=64) = 128 KiB.
//
// READ-COMPLETION LEDGER (which phase last ds_reads each region):
//   buf0 As: P3 (each wave reads rows wm..wm+63 at P1, wm+64..wm+127 at P3)
//   buf0 Bs: P2   buf1 As: P7   buf1 Bs: P6
// => safe stage slots (stage must sit >=1 barrier after last read):
//   P1: A-h0(odd tile)->buf1    P2: A-h1(odd)->buf1      [buf1 As free since prev P7]
//   P3: B-h0(next even)->buf0   P4: B-h1(next even)->buf0 [buf0 Bs free after P2]
//   P5: A-h0(next even)->buf0   P6: A-h1(next even)->buf0 [buf0 As free after P3]
//   P7: B-h0(next odd)->buf1    P8: B-h1(next odd)->buf1  [buf1 Bs free after P6]
// vmcnt ledger (2 loads per stage, per wave):
//   at P4: outstanding after wait = P3+P4 loads = 4 -> vmcnt(4) proves stages
//          through P2 landed before P5 reads buf1 (odd tile complete).
//   at P8: outstanding after wait = P7+P8 loads = 4 -> vmcnt(4) proves stages
//          through P6 landed before next P1 reads buf0 (even tile complete).
// Swizzle: LDS chunk index XOR (row&7); inverse applied on the global SOURCE
// address (global_load_lds dest must be linear), same involution on ds_read.

#define WAIT_LGKM0()                                                          \
  do { asm volatile("s_waitcnt lgkmcnt(0)" ::: "memory");                     \
       __builtin_amdgcn_sched_barrier(0); } while (0)
#define WAIT_VM4()                                                            \
  do { asm volatile("s_waitcnt vmcnt(4)" ::: "memory");                       \
       __builtin_amdgcn_sched_barrier(0); } while (0)
#define BARX() __builtin_amdgcn_s_barrier()

#define LDA4(buf, mib)                                                        \
  _Pragma("unroll") for (int j = 0; j < 4; ++j) {                             \
    const int row_ = wm + ((mib) + j) * 16 + rrow;                            \
    a[j][0] = As[buf][row_ * 8 + (quad ^ (row_ & 7))];                        \
    a[j][1] = As[buf][row_ * 8 + ((quad + 4) ^ (row_ & 7))];                  \
  }

#define LDB2(bb, buf, nib)                                                    \
  _Pragma("unroll") for (int j = 0; j < 2; ++j) {                             \
    const int row_ = wn + ((nib) + j) * 16 + rrow;                            \
    bb[j][0] = Bs[buf][row_ * 8 + (quad ^ (row_ & 7))];                       \
    bb[j][1] = Bs[buf][row_ * 8 + ((quad + 4) ^ (row_ & 7))];                 \
  }

#define MFMAQ(mb, nb, bb)                                                     \
  do {                                                                        \
    __builtin_amdgcn_s_setprio(1);                                            \
    _Pragma("unroll") for (int mi = 0; mi < 4; ++mi)                          \
      _Pragma("unroll") for (int ni = 0; ni < 2; ++ni)                        \
        _Pragma("unroll") for (int kk = 0; kk < 2; ++kk)                      \
          acc[(mb) + mi][(nb) + ni] = __builtin_amdgcn_mfma_f32_16x16x32_f16( \
              a[mi][kk], bb[ni][kk], acc[(mb) + mi][(nb) + ni], 0, 0, 0);     \
    __builtin_amdgcn_s_setprio(0);                                            \
  } while (0)

#define STAGE_A(buf, h, koff)                                                 \
  do {                                                                        \
    GLOAD_LDS16(XH + aOff[h][0] + (koff), &As[buf][(h)*1024 + wave * 64]);    \
    GLOAD_LDS16(XH + aOff[h][1] + (koff), &As[buf][(h)*1024 + 512 + wave*64]);\
  } while (0)
#define STAGE_B(buf, h, koff)                                                 \
  do {                                                                        \
    GLOAD_LDS16(WH + bOff[h][0] + (koff), &Bs[buf][(h)*1024 + wave * 64]);    \
    GLOAD_LDS16(WH + bOff[h][1] + (koff), &Bs[buf][(h)*1024 + 512 + wave*64]);\
  } while (0)

__global__ __launch_bounds__(512, 2) void gemm_f16_8p(
    const _Float16* __restrict__ XH, const _Float16* __restrict__ WH,
    const float* __restrict__ Bias, float* __restrict__ C) {
  __shared__ half8 As[2][2048];   // [buf][row*8 + swz-chunk], 256 rows x 64 k
  __shared__ half8 Bs[2][2048];

  const int tid  = threadIdx.x;
  const int lane = tid & 63;
  const int wave = tid >> 6;
  const int wm   = (wave >> 2) * 128;  // wave M origin within tile
  const int wn   = (wave & 3) * 64;    // wave N origin within tile
  const int rrow = lane & 15;
  const int quad = lane >> 4;

  // XCD-aware bijective swizzle: 768 blocks, 768 % 8 == 0.
  const int bid = blockIdx.x;
  const int swz = (bid & 7) * 96 + (bid >> 3);
  const int m0  = (swz / 48) * 256;
  const int n0  = (swz % 48) * 256;

  // Per-lane inverse-swizzled global source offsets (elements).
  // LDS slot s = r*512 + tid within a 128-row half; row = s>>3,
  // global chunk c = (s&7) ^ (row&7).
  uint32_t aOff[2][2], bOff[2][2];
  #pragma unroll
  for (int h = 0; h < 2; ++h)
    #pragma unroll
    for (int r = 0; r < 2; ++r) {
      const int slot = r * 512 + tid;
      const int row  = slot >> 3;
      const int c    = (slot & 7) ^ (row & 7);
      aOff[h][r] = (uint32_t)((m0 + h * 128 + row) * K_DIM + c * 8);
      bOff[h][r] = (uint32_t)((n0 + h * 128 + row) * K_DIM + c * 8);
    }

  f32x4 acc[8][4];
  #pragma unroll
  for (int i = 0; i < 8; ++i)
    #pragma unroll
    for (int j = 0; j < 4; ++j)
      acc[i][j] = (f32x4){0.f, 0.f, 0.f, 0.f};

  half8 a[4][2], bl[2][2], bh[2][2];

  // Prologue ("iteration -1" P3..P8): tile0 fully -> buf0 (8 loads, oldest),
  // then tile1 B -> buf1 (4 loads). vmcnt(4) -> tile0's 8 landed.
  STAGE_B(0, 0, 0);  STAGE_B(0, 1, 0);  STAGE_A(0, 0, 0);  STAGE_A(0, 1, 0);
  STAGE_B(1, 0, 64); STAGE_B(1, 1, 64);
  WAIT_VM4();
  BARX();

  // 32 iterations x 2 K-tiles (NT = 64).
  for (int it = 0; it < 32; ++it) {
    const int k1  = it * 128 + 64;                  // current odd tile
    const int kp0 = (it < 31) ? it * 128 + 128 : 0; // prefetch tile 2it+2
    const int kp1 = (it < 31) ? it * 128 + 192 : 0; // prefetch tile 2it+3

    // P1: (Mlo,Nlo) of buf0; stage A-h0(current odd) -> buf1
    LDA4(0, 0);
    LDB2(bl, 0, 0);
    STAGE_A(1, 0, k1);
    BARX(); WAIT_LGKM0();
    MFMAQ(0, 0, bl);
    BARX();

    // P2: (Mlo,Nhi); stage A-h1(current odd) -> buf1
    LDB2(bh, 0, 2);
    STAGE_A(1, 1, k1);
    BARX(); WAIT_LGKM0();
    MFMAQ(0, 2, bh);
    BARX();

    // P3: (Mhi,Nhi); stage B-h0(next even) -> buf0  [buf0 Bs free after P2]
    LDA4(0, 4);
    STAGE_B(0, 0, kp0);
    BARX(); WAIT_LGKM0();
    MFMAQ(4, 2, bh);
    BARX();

    // P4: (Mhi,Nlo) from regs; stage B-h1(next even) -> buf0; vmcnt(4)
    // -> odd tile (prev P7/P8 B + P1/P2 A) fully landed before P5 reads.
    STAGE_B(0, 1, kp0);
    BARX();
    MFMAQ(4, 0, bl);
    WAIT_VM4();
    BARX();

    // P5: (Mlo,Nlo) of buf1; stage A-h0(next even) -> buf0 [buf0 As free after P3]
    LDA4(1, 0);
    LDB2(bl, 1, 0);
    STAGE_A(0, 0, kp0);
    BARX(); WAIT_LGKM0();
    MFMAQ(0, 0, bl);
    BARX();

    // P6: (Mlo,Nhi); stage A-h1(next even) -> buf0
    LDB2(bh, 1, 2);
    STAGE_A(0, 1, kp0);
    BARX(); WAIT_LGKM0();
    MFMAQ(0, 2, bh);
    BARX();

    // P7: (Mhi,Nhi); stage B-h0(next odd) -> buf1  [buf1 Bs free after P6]
    LDA4(1, 4);
    STAGE_B(1, 0, kp1);
    BARX(); WAIT_LGKM0();
    MFMAQ(4, 2, bh);
    BARX();

    // P8: (Mhi,Nlo) from regs; stage B-h1(next odd) -> buf1; vmcnt(4)
    // -> next even tile (P3..P6 stages, buf0) landed before next P1 reads.
    STAGE_B(1, 1, kp1);
    BARX();
    MFMAQ(4, 0, bl);
    WAIT_VM4();
    BARX();
  }

  // Epilogue: C/D layout col(n)=lane&15, row(m)=quad*4+reg [m89]
  #pragma unroll
  for (int ni = 0; ni < 4; ++ni) {
    const int n = n0 + wn + ni * 16 + rrow;
    const float bv = Bias[n];
    #pragma unroll
    for (int mi = 0; mi < 8; ++mi) {
      const int mbase = m0 + wm + mi * 16 + quad * 4;
      #pragma unroll
      for (int rr = 0; rr < 4; ++rr) {
        C[(size_t)(mbase + rr) * N_DIM + n] = acc[mi][ni][rr] + bv;
      }
    }
  }
}

// ---------------- fallback (previous verified 128^2 kernel) ----------------
template <bool PRE>
__global__ __launch_bounds__(256) void awq_gemm(
    const float* __restrict__ X, const _Float16* __restrict__ XH,
    const int* __restrict__ Q, const float* __restrict__ S,
    const float* __restrict__ Bias, float* __restrict__ C) {
  __shared__ half8 Asf[BM * 8];
  __shared__ half8 Bsf[BN * 8];

  const int tid  = threadIdx.x;
  const int lane = tid & 63;
  const int wave = tid >> 6;
  const int wm   = (wave >> 1) * 64;
  const int wn   = (wave & 1) * 64;
  const int m0   = blockIdx.y * BM;
  const int n0   = blockIdx.x * BN;
  const int rrow = lane & 15;
  const int quad = lane >> 4;

  const _Float16* a_gp[4];
  if (PRE) {
    #pragma unroll
    for (int r = 0; r < 4; ++r) {
      const int slot = (wave * 4 + r) * 64 + lane;
      const int row  = slot >> 3;
      const int c    = (slot & 7) ^ (row & 7);
      a_gp[r] = XH + (size_t)(m0 + row) * K_DIM + c * 8;
    }
  }

  int brow[4], bcol[4];
  #pragma unroll
  for (int r = 0; r < 4; ++r) {
    const int idx = tid + 256 * r;
    brow[r] = idx >> 3;
    bcol[r] = idx & 7;
  }

  f32x4 acc[4][4];
  #pragma unroll
  for (int i = 0; i < 4; ++i)
    #pragma unroll
    for (int j = 0; j < 4; ++j)
      acc[i][j] = (f32x4){0.f, 0.f, 0.f, 0.f};

  for (int k0 = 0; k0 < K_DIM; k0 += BK) {
    if (PRE) {
      #pragma unroll
      for (int r = 0; r < 4; ++r)
        GLOAD_LDS16(a_gp[r] + k0, &Asf[(wave * 4 + r) * 64]);
    } else {
      #pragma unroll
      for (int r = 0; r < 4; ++r) {
        const int ch  = tid + 256 * r;
        const int row = ch >> 3;
        const int c   = ch & 7;
        const float* p = X + (size_t)(m0 + row) * K_DIM + k0 + c * 8;
        f32x4 v0 = *(const f32x4*)p;
        f32x4 v1 = *(const f32x4*)(p + 4);
        union { fp16x2 h2[4]; half8 h8; } u;
        u.h2[0] = __builtin_amdgcn_cvt_pkrtz(v0.x, v0.y);
        u.h2[1] = __builtin_amdgcn_cvt_pkrtz(v0.z, v0.w);
        u.h2[2] = __builtin_amdgcn_cvt_pkrtz(v1.x, v1.y);
        u.h2[3] = __builtin_amdgcn_cvt_pkrtz(v1.z, v1.w);
        Asf[row * 8 + (c ^ (row & 7))] = u.h8;
      }
    }
    #pragma unroll
    for (int r = 0; r < 4; ++r) {
      const int row = brow[r];
      const int c   = bcol[r];
      const uint32_t q =
          (uint32_t)Q[(size_t)(n0 + row) * (K_DIM / 8) + (k0 >> 3) + c];
      const float s = S[(size_t)(n0 + row) * (K_DIM / 128) + (k0 >> 7)];
      Bsf[row * 8 + (c ^ (row & 7))] = dequant8(q, (_Float16)s);
    }
    __syncthreads();

    #pragma unroll
    for (int kk = 0; kk < 2; ++kk) {
      const int kch = kk * 4 + quad;
      half8 a[4], b[4];
      #pragma unroll
      for (int mi = 0; mi < 4; ++mi) {
        const int row = wm + mi * 16 + rrow;
        a[mi] = Asf[row * 8 + (kch ^ (row & 7))];
      }
      #pragma unroll
      for (int ni = 0; ni < 4; ++ni) {
        const int row = wn + ni * 16 + rrow;
        b[ni] = Bsf[row * 8 + (kch ^ (row & 7))];
      }
      #pragma unroll
      for (int mi = 0; mi < 4; ++mi)
        #pragma unroll
        for (int ni = 0; ni < 4; ++ni)
          acc[mi][ni] = __builtin_amdgcn_mfma_f32_16x16x32_f16(
              a[mi], b[ni], acc[mi][ni], 0, 0, 0);
    }
    __syncthreads();
  }

  #pragma unroll
  for (int ni = 0; ni < 4; ++ni) {
    const int n = n0 + wn + ni * 16 + rrow;
    const float bv = Bias[n];
    #pragma unroll
    for (int mi = 0; mi < 4; ++mi) {
      const int mbase = m0 + wm + mi * 16 + quad * 4;
      #pragma unroll
      for (int rr = 0; rr < 4; ++rr) {
        C[(size_t)(mbase + rr) * N_DIM + n] = acc[mi][ni][rr] + bv;
      }
    }
  }
}

extern "C" void kernel_launch(void* const* d_in, const int* in_sizes, int n_in,
                              void* d_out, int out_size, void* d_ws, size_t ws_size,
                              hipStream_t stream) {
  const float* X    = (const float*)d_in[0];
  const int*   Q    = (const int*)d_in[1];
  const float* S    = (const float*)d_in[2];
  const float* Bias = (const float*)d_in[3];
  float* C = (float*)d_out;

  const size_t needXH = (size_t)M_DIM * K_DIM * sizeof(_Float16);  // 32 MiB
  const size_t needWH = (size_t)N_DIM * K_DIM * sizeof(_Float16);  // 96 MiB
  if (ws_size >= needXH + needWH) {
    _Float16* XH = (_Float16*)d_ws;
    _Float16* WH = (_Float16*)((char*)d_ws + needXH);
    prep<<<dim3(8192 + 24576), dim3(256), 0, stream>>>(X, XH, Q, S, WH);
    gemm_f16_8p<<<dim3(768), dim3(512), 0, stream>>>(XH, WH, Bias, C);
  } else if (ws_size >= needXH) {
    _Float16* XH = (_Float16*)d_ws;
    cvt_f32_f16<<<(M_DIM * (size_t)K_DIM) / 8 / 256, 256, 0, stream>>>(X, XH);
    awq_gemm<true><<<dim3(N_DIM / BN, M_DIM / BM), dim3(256), 0, stream>>>(
        X, XH, Q, S, Bias, C);
  } else {
    awq_gemm<false><<<dim3(N_DIM / BN, M_DIM / BM), dim3(256), 0, stream>>>(
        X, nullptr, Q, S, Bias, C);
  }
}

// Round 4
// 614.004 us; speedup vs baseline: 1.3077x; 1.0146x over previous
//
#include <hip/hip_runtime.h>
#include <stdint.h>

#define M_DIM 4096
#define K_DIM 4096
#define N_DIM 12288

// fallback tile (old verified 128^2 kernel)
#define BM 128
#define BN 128
#define BK 64

typedef __attribute__((ext_vector_type(8))) _Float16 half8;
typedef __attribute__((ext_vector_type(2))) __fp16 fp16x2;
typedef __attribute__((ext_vector_type(4))) float f32x4;

#define GLOAD_LDS16(gp, lp)                                                   \
  __builtin_amdgcn_global_load_lds(                                           \
      (const __attribute__((address_space(1))) void*)(gp),                    \
      (__attribute__((address_space(3))) void*)(lp), 16, 0, 0)

// 8 nibbles (high-first) -> 8 f16 weights, single-rounded:
// h = 1024 + n exactly (0x6400|n); (h - 1024) is exact; one mul rounds.
static __device__ __forceinline__ half8 dequant8(uint32_t q, _Float16 sh) {
  union { uint32_t u[4]; half8 h; } w;
  w.u[0] = 0x64006400u | ((q >> 28) & 0xFu) | ((q >> 8)  & 0xF0000u);
  w.u[1] = 0x64006400u | ((q >> 20) & 0xFu) | ( q         & 0xF0000u);
  w.u[2] = 0x64006400u | ((q >> 12) & 0xFu) | ((q << 8)  & 0xF0000u);
  w.u[3] = 0x64006400u | ((q >> 4)  & 0xFu) | ((q << 16) & 0xF0000u);
  half8 hv = w.h;
  half8 mm, ss;
  #pragma unroll
  for (int i = 0; i < 8; ++i) { mm[i] = (_Float16)(-1024.0f); ss[i] = sh; }
  return (hv + mm) * ss;   // pk_add_f16 + pk_mul_f16, vectorized
}

// Merged prep: blocks [0,8192) convert X f32->f16; blocks [8192,32768)
// dequantize W (one thread per packed int32 -> 16 B f16 store).
__global__ __launch_bounds__(256) void prep(const float* __restrict__ X,
                                            _Float16* __restrict__ XH,
                                            const int* __restrict__ Q,
                                            const float* __restrict__ S,
                                            _Float16* __restrict__ WH) {
  const int bid = blockIdx.x;
  if (bid < 8192) {
    const size_t i = ((size_t)bid * 256 + threadIdx.x) * 8;
    f32x4 v0 = *(const f32x4*)(X + i);
    f32x4 v1 = *(const f32x4*)(X + i + 4);
    union { fp16x2 h2[4]; half8 h8; } u;
    u.h2[0] = __builtin_amdgcn_cvt_pkrtz(v0.x, v0.y);
    u.h2[1] = __builtin_amdgcn_cvt_pkrtz(v0.z, v0.w);
    u.h2[2] = __builtin_amdgcn_cvt_pkrtz(v1.x, v1.y);
    u.h2[3] = __builtin_amdgcn_cvt_pkrtz(v1.z, v1.w);
    *(half8*)(XH + i) = u.h8;
  } else {
    const int idx = (bid - 8192) * 256 + threadIdx.x;  // [0, 12288*512)
    const int o = idx >> 9;    // output row (O)
    const int c = idx & 511;   // chunk within row (I/8)
    const uint32_t q = (uint32_t)Q[idx];
    const float s = S[o * (K_DIM / 128) + (c >> 4)];
    *(half8*)(WH + (size_t)o * K_DIM + c * 8) = dequant8(q, (_Float16)s);
  }
}

// f32->f16 only (fallback path)
__global__ __launch_bounds__(256) void cvt_f32_f16(const float* __restrict__ X,
                                                   _Float16* __restrict__ XH) {
  const size_t i = ((size_t)blockIdx.x * 256 + threadIdx.x) * 8;
  f32x4 v0 = *(const f32x4*)(X + i);
  f32x4 v1 = *(const f32x4*)(X + i + 4);
  union { fp16x2 h2[4]; half8 h8; } u;
  u.h2[0] = __builtin_amdgcn_cvt_pkrtz(v0.x, v0.y);
  u.h2[1] = __builtin_amdgcn_cvt_pkrtz(v0.z, v0.w);
  u.h2[2] = __builtin_amdgcn_cvt_pkrtz(v1.x, v1.y);
  u.h2[3] = __builtin_amdgcn_cvt_pkrtz(v1.z, v1.w);
  *(half8*)(XH + i) = u.h8;
}

// ===================== 256x256 8-phase GEMM (T2+T3+T4+T5) =====================
// 512 threads = 8 waves (2M x 4N), per-wave output 128x64.
// LDS: double-buffered A/B K-tiles (BK=64) = 128 KiB.
//
// READ-COMPLETION LEDGER (which phase last ds_reads each region):
//   buf0 As: P3 (each wave reads rows wm..wm+63 at P1, wm+64..wm+127 at P3)
//   buf0 Bs: P2   buf1 As: P7   buf1 Bs: P6
// => safe stage slots (stage must sit >=1 barrier after last read):
//   P1: A-h0(odd tile)->buf1    P2: A-h1(odd)->buf1      [buf1 As free since prev P7]
//   P3: B-h0(next even)->buf0   P4: B-h1(next even)->buf0 [buf0 Bs free after P2]
//   P5: A-h0(next even)->buf0   P6: A-h1(next even)->buf0 [buf0 As free after P3]
//   P7: B-h0(next odd)->buf1    P8: B-h1(next odd)->buf1  [buf1 Bs free after P6]
// vmcnt ledger (2 loads per stage, per wave):
//   at P4: outstanding after wait = P3+P4 loads = 4 -> vmcnt(4) proves stages
//          through P2 landed before P5 reads buf1 (odd tile complete).
//   at P8: outstanding after wait = P7+P8 loads = 4 -> vmcnt(4) proves stages
//          through P6 landed before next P1 reads buf0 (even tile complete).
// Swizzle: LDS chunk index XOR (row&7); inverse applied on the global SOURCE
// address (global_load_lds dest must be linear), same involution on ds_read.
// Locality (R4): m-fastest block order -> concurrent blocks share ALL of A
// (32 MB, L3-resident) and cluster W-panel reuse; nt C-stores keep the 208 MB
// C stream from evicting A/B out of L2/L3.

#define WAIT_LGKM0()                                                          \
  do { asm volatile("s_waitcnt lgkmcnt(0)" ::: "memory");                     \
       __builtin_amdgcn_sched_barrier(0); } while (0)
#define WAIT_VM4()                                                            \
  do { asm volatile("s_waitcnt vmcnt(4)" ::: "memory");                       \
       __builtin_amdgcn_sched_barrier(0); } while (0)
#define BARX() __builtin_amdgcn_s_barrier()

#define LDA4(buf, mib)                                                        \
  _Pragma("unroll") for (int j = 0; j < 4; ++j) {                             \
    const int row_ = wm + ((mib) + j) * 16 + rrow;                            \
    a[j][0] = As[buf][row_ * 8 + (quad ^ (row_ & 7))];                        \
    a[j][1] = As[buf][row_ * 8 + ((quad + 4) ^ (row_ & 7))];                  \
  }

#define LDB2(bb, buf, nib)                                                    \
  _Pragma("unroll") for (int j = 0; j < 2; ++j) {                             \
    const int row_ = wn + ((nib) + j) * 16 + rrow;                            \
    bb[j][0] = Bs[buf][row_ * 8 + (quad ^ (row_ & 7))];                       \
    bb[j][1] = Bs[buf][row_ * 8 + ((quad + 4) ^ (row_ & 7))];                 \
  }

#define MFMAQ(mb, nb, bb)                                                     \
  do {                                                                        \
    __builtin_amdgcn_s_setprio(1);                                            \
    _Pragma("unroll") for (int mi = 0; mi < 4; ++mi)                          \
      _Pragma("unroll") for (int ni = 0; ni < 2; ++ni)                        \
        _Pragma("unroll") for (int kk = 0; kk < 2; ++kk)                      \
          acc[(mb) + mi][(nb) + ni] = __builtin_amdgcn_mfma_f32_16x16x32_f16( \
              a[mi][kk], bb[ni][kk], acc[(mb) + mi][(nb) + ni], 0, 0, 0);     \
    __builtin_amdgcn_s_setprio(0);                                            \
  } while (0)

#define STAGE_A(buf, h, koff)                                                 \
  do {                                                                        \
    GLOAD_LDS16(XH + aOff[h][0] + (koff), &As[buf][(h)*1024 + wave * 64]);    \
    GLOAD_LDS16(XH + aOff[h][1] + (koff), &As[buf][(h)*1024 + 512 + wave*64]);\
  } while (0)
#define STAGE_B(buf, h, koff)                                                 \
  do {                                                                        \
    GLOAD_LDS16(WH + bOff[h][0] + (koff), &Bs[buf][(h)*1024 + wave * 64]);    \
    GLOAD_LDS16(WH + bOff[h][1] + (koff), &Bs[buf][(h)*1024 + 512 + wave*64]);\
  } while (0)

__global__ __launch_bounds__(512, 2) void gemm_f16_8p(
    const _Float16* __restrict__ XH, const _Float16* __restrict__ WH,
    const float* __restrict__ Bias, float* __restrict__ C) {
  __shared__ half8 As[2][2048];   // [buf][row*8 + swz-chunk], 256 rows x 64 k
  __shared__ half8 Bs[2][2048];

  const int tid  = threadIdx.x;
  const int lane = tid & 63;
  const int wave = tid >> 6;
  const int wm   = (wave >> 2) * 128;  // wave M origin within tile
  const int wn   = (wave & 3) * 64;    // wave N origin within tile
  const int rrow = lane & 15;
  const int quad = lane >> 4;

  // XCD-aware bijective swizzle: 768 blocks, 768 % 8 == 0.
  // m-FASTEST order: concurrent blocks cover all 16 m-tiles (A L3-resident)
  // and cluster the 16 readers of each W n-panel close in time.
  const int bid = blockIdx.x;
  const int swz = (bid & 7) * 96 + (bid >> 3);
  const int m0  = (swz & 15) * 256;   // 16 m-tiles, fastest
  const int n0  = (swz >> 4) * 256;   // 48 n-tiles

  // Per-lane inverse-swizzled global source offsets (elements).
  // LDS slot s = r*512 + tid within a 128-row half; row = s>>3,
  // global chunk c = (s&7) ^ (row&7).
  uint32_t aOff[2][2], bOff[2][2];
  #pragma unroll
  for (int h = 0; h < 2; ++h)
    #pragma unroll
    for (int r = 0; r < 2; ++r) {
      const int slot = r * 512 + tid;
      const int row  = slot >> 3;
      const int c    = (slot & 7) ^ (row & 7);
      aOff[h][r] = (uint32_t)((m0 + h * 128 + row) * K_DIM + c * 8);
      bOff[h][r] = (uint32_t)((n0 + h * 128 + row) * K_DIM + c * 8);
    }

  f32x4 acc[8][4];
  #pragma unroll
  for (int i = 0; i < 8; ++i)
    #pragma unroll
    for (int j = 0; j < 4; ++j)
      acc[i][j] = (f32x4){0.f, 0.f, 0.f, 0.f};

  half8 a[4][2], bl[2][2], bh[2][2];

  // Prologue ("iteration -1" P3..P8): tile0 fully -> buf0 (8 loads, oldest),
  // then tile1 B -> buf1 (4 loads). vmcnt(4) -> tile0's 8 landed.
  STAGE_B(0, 0, 0);  STAGE_B(0, 1, 0);  STAGE_A(0, 0, 0);  STAGE_A(0, 1, 0);
  STAGE_B(1, 0, 64); STAGE_B(1, 1, 64);
  WAIT_VM4();
  BARX();

  // 32 iterations x 2 K-tiles (NT = 64).
  for (int it = 0; it < 32; ++it) {
    const int k1  = it * 128 + 64;                  // current odd tile
    const int kp0 = (it < 31) ? it * 128 + 128 : 0; // prefetch tile 2it+2
    const int kp1 = (it < 31) ? it * 128 + 192 : 0; // prefetch tile 2it+3

    // P1: (Mlo,Nlo) of buf0; stage A-h0(current odd) -> buf1
    LDA4(0, 0);
    LDB2(bl, 0, 0);
    STAGE_A(1, 0, k1);
    BARX(); WAIT_LGKM0();
    MFMAQ(0, 0, bl);
    BARX();

    // P2: (Mlo,Nhi); stage A-h1(current odd) -> buf1
    LDB2(bh, 0, 2);
    STAGE_A(1, 1, k1);
    BARX(); WAIT_LGKM0();
    MFMAQ(0, 2, bh);
    BARX();

    // P3: (Mhi,Nhi); stage B-h0(next even) -> buf0  [buf0 Bs free after P2]
    LDA4(0, 4);
    STAGE_B(0, 0, kp0);
    BARX(); WAIT_LGKM0();
    MFMAQ(4, 2, bh);
    BARX();

    // P4: (Mhi,Nlo) from regs; stage B-h1(next even) -> buf0; vmcnt(4)
    // -> odd tile (prev P7/P8 B + P1/P2 A) fully landed before P5 reads.
    STAGE_B(0, 1, kp0);
    BARX();
    MFMAQ(4, 0, bl);
    WAIT_VM4();
    BARX();

    // P5: (Mlo,Nlo) of buf1; stage A-h0(next even) -> buf0 [buf0 As free after P3]
    LDA4(1, 0);
    LDB2(bl, 1, 0);
    STAGE_A(0, 0, kp0);
    BARX(); WAIT_LGKM0();
    MFMAQ(0, 0, bl);
    BARX();

    // P6: (Mlo,Nhi); stage A-h1(next even) -> buf0
    LDB2(bh, 1, 2);
    STAGE_A(0, 1, kp0);
    BARX(); WAIT_LGKM0();
    MFMAQ(0, 2, bh);
    BARX();

    // P7: (Mhi,Nhi); stage B-h0(next odd) -> buf1  [buf1 Bs free after P6]
    LDA4(1, 4);
    STAGE_B(1, 0, kp1);
    BARX(); WAIT_LGKM0();
    MFMAQ(4, 2, bh);
    BARX();

    // P8: (Mhi,Nlo) from regs; stage B-h1(next odd) -> buf1; vmcnt(4)
    // -> next even tile (P3..P6 stages, buf0) landed before next P1 reads.
    STAGE_B(1, 1, kp1);
    BARX();
    MFMAQ(4, 0, bl);
    WAIT_VM4();
    BARX();
  }

  // Epilogue: C/D layout col(n)=lane&15, row(m)=quad*4+reg [m89].
  // Non-temporal stores: C (208 MB stream) must not evict A/B from L2/L3.
  #pragma unroll
  for (int ni = 0; ni < 4; ++ni) {
    const int n = n0 + wn + ni * 16 + rrow;
    const float bv = Bias[n];
    #pragma unroll
    for (int mi = 0; mi < 8; ++mi) {
      const int mbase = m0 + wm + mi * 16 + quad * 4;
      #pragma unroll
      for (int rr = 0; rr < 4; ++rr) {
        __builtin_nontemporal_store(acc[mi][ni][rr] + bv,
                                    &C[(size_t)(mbase + rr) * N_DIM + n]);
      }
    }
  }
}

// ---------------- fallback (previous verified 128^2 kernel) ----------------
template <bool PRE>
__global__ __launch_bounds__(256) void awq_gemm(
    const float* __restrict__ X, const _Float16* __restrict__ XH,
    const int* __restrict__ Q, const float* __restrict__ S,
    const float* __restrict__ Bias, float* __restrict__ C) {
  __shared__ half8 Asf[BM * 8];
  __shared__ half8 Bsf[BN * 8];

  const int tid  = threadIdx.x;
  const int lane = tid & 63;
  const int wave = tid >> 6;
  const int wm   = (wave >> 1) * 64;
  const int wn   = (wave & 1) * 64;
  const int m0   = blockIdx.y * BM;
  const int n0   = blockIdx.x * BN;
  const int rrow = lane & 15;
  const int quad = lane >> 4;

  const _Float16* a_gp[4];
  if (PRE) {
    #pragma unroll
    for (int r = 0; r < 4; ++r) {
      const int slot = (wave * 4 + r) * 64 + lane;
      const int row  = slot >> 3;
      const int c    = (slot & 7) ^ (row & 7);
      a_gp[r] = XH + (size_t)(m0 + row) * K_DIM + c * 8;
    }
  }

  int brow[4], bcol[4];
  #pragma unroll
  for (int r = 0; r < 4; ++r) {
    const int idx = tid + 256 * r;
    brow[r] = idx >> 3;
    bcol[r] = idx & 7;
  }

  f32x4 acc[4][4];
  #pragma unroll
  for (int i = 0; i < 4; ++i)
    #pragma unroll
    for (int j = 0; j < 4; ++j)
      acc[i][j] = (f32x4){0.f, 0.f, 0.f, 0.f};

  for (int k0 = 0; k0 < K_DIM; k0 += BK) {
    if (PRE) {
      #pragma unroll
      for (int r = 0; r < 4; ++r)
        GLOAD_LDS16(a_gp[r] + k0, &Asf[(wave * 4 + r) * 64]);
    } else {
      #pragma unroll
      for (int r = 0; r < 4; ++r) {
        const int ch  = tid + 256 * r;
        const int row = ch >> 3;
        const int c   = ch & 7;
        const float* p = X + (size_t)(m0 + row) * K_DIM + k0 + c * 8;
        f32x4 v0 = *(const f32x4*)p;
        f32x4 v1 = *(const f32x4*)(p + 4);
        union { fp16x2 h2[4]; half8 h8; } u;
        u.h2[0] = __builtin_amdgcn_cvt_pkrtz(v0.x, v0.y);
        u.h2[1] = __builtin_amdgcn_cvt_pkrtz(v0.z, v0.w);
        u.h2[2] = __builtin_amdgcn_cvt_pkrtz(v1.x, v1.y);
        u.h2[3] = __builtin_amdgcn_cvt_pkrtz(v1.z, v1.w);
        Asf[row * 8 + (c ^ (row & 7))] = u.h8;
      }
    }
    #pragma unroll
    for (int r = 0; r < 4; ++r) {
      const int row = brow[r];
      const int c   = bcol[r];
      const uint32_t q =
          (uint32_t)Q[(size_t)(n0 + row) * (K_DIM / 8) + (k0 >> 3) + c];
      const float s = S[(size_t)(n0 + row) * (K_DIM / 128) + (k0 >> 7)];
      Bsf[row * 8 + (c ^ (row & 7))] = dequant8(q, (_Float16)s);
    }
    __syncthreads();

    #pragma unroll
    for (int kk = 0; kk < 2; ++kk) {
      const int kch = kk * 4 + quad;
      half8 a[4], b[4];
      #pragma unroll
      for (int mi = 0; mi < 4; ++mi) {
        const int row = wm + mi * 16 + rrow;
        a[mi] = Asf[row * 8 + (kch ^ (row & 7))];
      }
      #pragma unroll
      for (int ni = 0; ni < 4; ++ni) {
        const int row = wn + ni * 16 + rrow;
        b[ni] = Bsf[row * 8 + (kch ^ (row & 7))];
      }
      #pragma unroll
      for (int mi = 0; mi < 4; ++mi)
        #pragma unroll
        for (int ni = 0; ni < 4; ++ni)
          acc[mi][ni] = __builtin_amdgcn_mfma_f32_16x16x32_f16(
              a[mi], b[ni], acc[mi][ni], 0, 0, 0);
    }
    __syncthreads();
  }

  #pragma unroll
  for (int ni = 0; ni < 4; ++ni) {
    const int n = n0 + wn + ni * 16 + rrow;
    const float bv = Bias[n];
    #pragma unroll
    for (int mi = 0; mi < 4; ++mi) {
      const int mbase = m0 + wm + mi * 16 + quad * 4;
      #pragma unroll
      for (int rr = 0; rr < 4; ++rr) {
        C[(size_t)(mbase + rr) * N_DIM + n] = acc[mi][ni][rr] + bv;
      }
    }
  }
}

extern "C" void kernel_launch(void* const* d_in, const int* in_sizes, int n_in,
                              void* d_out, int out_size, void* d_ws, size_t ws_size,
                              hipStream_t stream) {
  const float* X    = (const float*)d_in[0];
  const int*   Q    = (const int*)d_in[1];
  const float* S    = (const float*)d_in[2];
  const float* Bias = (const float*)d_in[3];
  float* C = (float*)d_out;

  const size_t needXH = (size_t)M_DIM * K_DIM * sizeof(_Float16);  // 32 MiB
  const size_t needWH = (size_t)N_DIM * K_DIM * sizeof(_Float16);  // 96 MiB
  if (ws_size >= needXH + needWH) {
    _Float16* XH = (_Float16*)d_ws;
    _Float16* WH = (_Float16*)((char*)d_ws + needXH);
    prep<<<dim3(8192 + 24576), dim3(256), 0, stream>>>(X, XH, Q, S, WH);
    gemm_f16_8p<<<dim3(768), dim3(512), 0, stream>>>(XH, WH, Bias, C);
  } else if (ws_size >= needXH) {
    _Float16* XH = (_Float16*)d_ws;
    cvt_f32_f16<<<(M_DIM * (size_t)K_DIM) / 8 / 256, 256, 0, stream>>>(X, XH);
    awq_gemm<true><<<dim3(N_DIM / BN, M_DIM / BM), dim3(256), 0, stream>>>(
        X, XH, Q, S, Bias, C);
  } else {
    awq_gemm<false><<<dim3(N_DIM / BN, M_DIM / BM), dim3(256), 0, stream>>>(
        X, nullptr, Q, S, Bias, C);
  }
}